// Round 1
// baseline (985.846 us; speedup 1.0000x reference)
//
#include <hip/hip_runtime.h>
#include <hip/hip_bf16.h>

typedef short short8 __attribute__((ext_vector_type(8)));
typedef float f32x4 __attribute__((ext_vector_type(4)));
typedef unsigned short ushort8_t __attribute__((ext_vector_type(8)));

#define AS3 __attribute__((address_space(3)))
#define AS1 __attribute__((address_space(1)))

__device__ __forceinline__ unsigned short f2bf(float f) {
  unsigned int u = __float_as_uint(f);
  u += 0x7FFFu + ((u >> 16) & 1u);   // round-to-nearest-even
  return (unsigned short)(u >> 16);
}

// ---------------- fp32 -> bf16 conversion (8 elems/thread) ----------------
__global__ __launch_bounds__(256) void cvt_bf16_kernel(const float* __restrict__ src,
                                                       unsigned short* __restrict__ dst,
                                                       int n8) {
  int idx = blockIdx.x * 256 + threadIdx.x;
  if (idx >= n8) return;
  const float4* s4 = (const float4*)src;
  float4 a = s4[2 * idx], b = s4[2 * idx + 1];
  ushort8_t o;
  o[0] = f2bf(a.x); o[1] = f2bf(a.y); o[2] = f2bf(a.z); o[3] = f2bf(a.w);
  o[4] = f2bf(b.x); o[5] = f2bf(b.y); o[6] = f2bf(b.z); o[7] = f2bf(b.w);
  ((ushort8_t*)dst)[idx] = o;
}

// ---------------- fused GEMM (bf16 MFMA) + max_p / mean_o -> f2f ----------------
// block: 576 threads = 9 waves in 3x3 grid; tile 144x144 (16 i-groups x 9 o, 16 j x 9 p)
// BK=32, single LDS buffer, global_load_lds width=16 staging (m97 structure).
__global__ __launch_bounds__(576) void gemm_f2f_kernel(const unsigned short* __restrict__ qb,
                                                       const unsigned short* __restrict__ tb,
                                                       float* __restrict__ f2f) {
  __shared__ __align__(16) char smem[36864];  // GEMM: A[144][32]@0 (9216B) B@9216; epilogue: scratch[48][144]@0, armax[144][16]@27648
  const int tid  = threadIdx.x;
  const int wv   = tid >> 6;
  const int lane = tid & 63;
  const int quad = lane >> 4;
  const int l16  = lane & 15;
  const int wr = wv / 3, wc = wv % 3;
  const int bi = blockIdx.y, bj = blockIdx.x;

  f32x4 acc[3][3];
#pragma unroll
  for (int a = 0; a < 3; ++a)
#pragma unroll
    for (int b = 0; b < 3; ++b) acc[a][b] = (f32x4){0.f, 0.f, 0.f, 0.f};

  // staging: wave wv loads 16 rows (1KB) of A and of B per K-iter.
  // lane l -> row l/4, 16B chunk l%4; LDS dest = wave-uniform base + lane*16.
  const int arow = bi * 144 + wv * 16 + (lane >> 2);
  const int brow = bj * 144 + wv * 16 + (lane >> 2);
  const int kcol = (lane & 3) * 8;
  const unsigned short* gA = qb + (size_t)arow * 3840 + kcol;
  const unsigned short* gB = tb + (size_t)brow * 3840 + kcol;
  AS3 char* lA = (AS3 char*)smem + wv * 1024;
  AS3 char* lB = (AS3 char*)smem + 9216 + wv * 1024;
  const unsigned short* Al = (const unsigned short*)smem;
  const unsigned short* Bl = (const unsigned short*)(smem + 9216);

  for (int kt = 0; kt < 120; ++kt) {
    __syncthreads();  // previous iter's ds_reads done before overwrite
    __builtin_amdgcn_global_load_lds((const AS1 void*)(gA + kt * 32), (AS3 void*)lA, 16, 0, 0);
    __builtin_amdgcn_global_load_lds((const AS1 void*)(gB + kt * 32), (AS3 void*)lB, 16, 0, 0);
    __syncthreads();  // drains vmcnt(0): staged data visible to all waves

    short8 a0 = *(const short8*)(Al + (wr * 48 +  0 + l16) * 32 + quad * 8);
    short8 a1 = *(const short8*)(Al + (wr * 48 + 16 + l16) * 32 + quad * 8);
    short8 a2 = *(const short8*)(Al + (wr * 48 + 32 + l16) * 32 + quad * 8);
#pragma unroll
    for (int sc = 0; sc < 3; ++sc) {
      short8 b = *(const short8*)(Bl + (wc * 48 + sc * 16 + l16) * 32 + quad * 8);
      acc[0][sc] = __builtin_amdgcn_mfma_f32_16x16x32_bf16(a0, b, acc[0][sc], 0, 0, 0);
      acc[1][sc] = __builtin_amdgcn_mfma_f32_16x16x32_bf16(a1, b, acc[1][sc], 0, 0, 0);
      acc[2][sc] = __builtin_amdgcn_mfma_f32_16x16x32_bf16(a2, b, acc[2][sc], 0, 0, 0);
    }
  }

  // -------- epilogue: 3 bands of 48 rows; rowmax over p, then mean over o --------
  __syncthreads();
  float* scratch = (float*)smem;            // [48][144]
  float* armax   = (float*)(smem + 27648);  // [144][16]
#pragma unroll 1
  for (int band = 0; band < 3; ++band) {
    if (wr == band) {
#pragma unroll
      for (int sr = 0; sr < 3; ++sr)
#pragma unroll
        for (int sc = 0; sc < 3; ++sc)
#pragma unroll
          for (int r = 0; r < 4; ++r)
            scratch[(sr * 16 + quad * 4 + r) * 144 + wc * 48 + sc * 16 + l16] = acc[sr][sc][r];
    }
    __syncthreads();
    for (int idx = tid; idx < 768; idx += 576) {  // 48 rows x 16 j
      int r = idx >> 4, j = idx & 15;
      const float* row = scratch + r * 144 + j * 9;
      float m = row[0];
#pragma unroll
      for (int p = 1; p < 9; ++p) m = fmaxf(m, row[p]);
      armax[(band * 48 + r) * 16 + j] = m;
    }
    __syncthreads();
  }
  if (tid < 256) {
    int i = tid >> 4, j = tid & 15;
    float s = 0.f;
#pragma unroll
    for (int o = 0; o < 9; ++o) s += armax[(i * 9 + o) * 16 + j];
    f2f[(bi * 16 + i) * 512 + bj * 16 + j] = s * (1.f / 9.f);
  }
}

// ---------------- conv1: 1->32ch 3x3 same + relu + 2x2 maxpool, 512^2 -> 256^2 ----------------
__global__ __launch_bounds__(256) void conv1_kernel(const float* __restrict__ in,
                                                    const float* __restrict__ w1,
                                                    const float* __restrict__ b1,
                                                    float* __restrict__ out) {
  int c  = blockIdx.x >> 8;
  int y2 = blockIdx.x & 255;
  int x2 = threadIdx.x;
  float w[9];
#pragma unroll
  for (int k = 0; k < 9; ++k) w[k] = w1[c * 9 + k];
  float bias = b1[c];
  float win[4][4];
  int yb = 2 * y2 - 1, xb = 2 * x2 - 1;
#pragma unroll
  for (int r = 0; r < 4; ++r) {
    int y = yb + r;
    bool yok = (unsigned)y < 512u;
#pragma unroll
    for (int cc = 0; cc < 4; ++cc) {
      int x = xb + cc;
      win[r][cc] = (yok && (unsigned)x < 512u) ? in[y * 512 + x] : 0.f;
    }
  }
  float m = -INFINITY;
#pragma unroll
  for (int a = 0; a < 2; ++a)
#pragma unroll
    for (int b = 0; b < 2; ++b) {
      float s = bias;
#pragma unroll
      for (int ky = 0; ky < 3; ++ky)
#pragma unroll
        for (int kx = 0; kx < 3; ++kx) s += win[a + ky][b + kx] * w[ky * 3 + kx];
      m = fmaxf(m, s);
    }
  out[c * 65536 + y2 * 256 + x2] = fmaxf(m, 0.f);  // relu(max) == max(relu)
}

// ---------------- conv2: 32->64ch 3x3 same + relu + 2x2 maxpool, 256^2 -> 128^2 ----------------
__global__ __launch_bounds__(256) void conv2_kernel(const float* __restrict__ in,
                                                    const float* __restrict__ w2,
                                                    const float* __restrict__ b2,
                                                    float* __restrict__ out) {
  int co   = blockIdx.x >> 6;
  int tile = blockIdx.x & 63;
  int ty = threadIdx.x >> 4, tx = threadIdx.x & 15;
  int y2 = (tile >> 3) * 16 + ty;
  int x2 = (tile & 7) * 16 + tx;
  float a00 = 0.f, a01 = 0.f, a10 = 0.f, a11 = 0.f;
  int yb = 2 * y2 - 1, xb = 2 * x2 - 1;
  for (int ci = 0; ci < 32; ++ci) {
    const float* wp = w2 + (co * 32 + ci) * 9;
    float w[9];
#pragma unroll
    for (int k = 0; k < 9; ++k) w[k] = wp[k];
    const float* ip = in + ci * 65536;
    float win[4][4];
#pragma unroll
    for (int r = 0; r < 4; ++r) {
      int y = yb + r;
      bool yok = (unsigned)y < 256u;
#pragma unroll
      for (int cc = 0; cc < 4; ++cc) {
        int x = xb + cc;
        win[r][cc] = (yok && (unsigned)x < 256u) ? ip[y * 256 + x] : 0.f;
      }
    }
#pragma unroll
    for (int ky = 0; ky < 3; ++ky)
#pragma unroll
      for (int kx = 0; kx < 3; ++kx) {
        float wk = w[ky * 3 + kx];
        a00 += win[0 + ky][0 + kx] * wk;
        a01 += win[0 + ky][1 + kx] * wk;
        a10 += win[1 + ky][0 + kx] * wk;
        a11 += win[1 + ky][1 + kx] * wk;
      }
  }
  float bias = b2[co];
  float m = fmaxf(fmaxf(a00, a01), fmaxf(a10, a11)) + bias;
  out[co * 16384 + y2 * 128 + x2] = fmaxf(m, 0.f);
}

// ---------------- conv3: 64->128ch 3x3 same + relu, 128^2 ----------------
__global__ __launch_bounds__(256) void conv3_kernel(const float* __restrict__ in,
                                                    const float* __restrict__ w3,
                                                    const float* __restrict__ b3,
                                                    float* __restrict__ out) {
  int co   = blockIdx.x >> 6;
  int tile = blockIdx.x & 63;
  int ty = threadIdx.x >> 4, tx = threadIdx.x & 15;
  int y = (tile >> 3) * 16 + ty;
  int x = (tile & 7) * 16 + tx;
  float acc = 0.f;
  for (int ci = 0; ci < 64; ++ci) {
    const float* wp = w3 + (co * 64 + ci) * 9;
    const float* ip = in + ci * 16384;
#pragma unroll
    for (int ky = 0; ky < 3; ++ky) {
      int yy = y + ky - 1;
      if ((unsigned)yy < 128u) {
#pragma unroll
        for (int kx = 0; kx < 3; ++kx) {
          int xx = x + kx - 1;
          if ((unsigned)xx < 128u) acc += ip[yy * 128 + xx] * wp[ky * 3 + kx];
        }
      }
    }
  }
  out[co * 16384 + y * 128 + x] = fmaxf(acc + b3[co], 0.f);
}

// ---------------- 1x1 conv (128->1) + bias + clip + rowmax over x ----------------
__global__ __launch_bounds__(128) void convf_kernel(const float* __restrict__ in,
                                                    const float* __restrict__ wf,
                                                    const float* __restrict__ bfp,
                                                    float* __restrict__ rowm) {
  int y = blockIdx.x;
  int x = threadIdx.x;
  float acc = 0.f;
  for (int ci = 0; ci < 128; ++ci) acc += in[ci * 16384 + y * 128 + x] * wf[ci];
  float s = acc + bfp[0];
  s = fminf(fmaxf(s, -1.f), 1.f);
  for (int off = 32; off; off >>= 1) s = fmaxf(s, __shfl_down(s, off, 64));
  __shared__ float red[2];
  if ((x & 63) == 0) red[x >> 6] = s;
  __syncthreads();
  if (x == 0) rowm[y] = fmaxf(red[0], red[1]);
}

// ---------------- mean over rows -> scalar ----------------
__global__ __launch_bounds__(128) void final_kernel(const float* __restrict__ rowm,
                                                    float* __restrict__ out) {
  int x = threadIdx.x;
  float v = rowm[x];
  for (int off = 32; off; off >>= 1) v += __shfl_down(v, off, 64);
  __shared__ float red[2];
  if ((x & 63) == 0) red[x >> 6] = v;
  __syncthreads();
  if (x == 0) out[0] = (red[0] + red[1]) * (1.f / 128.f);
}

extern "C" void kernel_launch(void* const* d_in, const int* in_sizes, int n_in,
                              void* d_out, int out_size, void* d_ws, size_t ws_size,
                              hipStream_t stream) {
  const float* q  = (const float*)d_in[0];
  const float* t  = (const float*)d_in[1];
  const float* w1 = (const float*)d_in[2];
  const float* b1 = (const float*)d_in[3];
  const float* w2 = (const float*)d_in[4];
  const float* b2 = (const float*)d_in[5];
  const float* w3 = (const float*)d_in[6];
  const float* b3 = (const float*)d_in[7];
  const float* wf = (const float*)d_in[8];
  const float* bf = (const float*)d_in[9];
  float* out = (float*)d_out;
  char* ws = (char*)d_ws;

  // workspace layout (bytes)
  unsigned short* qb  = (unsigned short*)(ws + 0);          // 4608x3840 bf16 = 35,389,440
  unsigned short* tb  = (unsigned short*)(ws + 35389440);   // 35,389,440
  float* f2f  = (float*)(ws + 70778880);                    // 512x512 f32  = 1,048,576
  float* x1   = (float*)(ws + 71827456);                    // 32x256x256   = 8,388,608
  float* x2b  = (float*)(ws + 80216064);                    // 64x128x128   = 4,194,304
  float* x3   = (float*)(ws + 84410368);                    // 128x128x128  = 8,388,608
  float* rowm = (float*)(ws + 92798976);                    // 128 f32

  cvt_bf16_kernel<<<8640, 256, 0, stream>>>(q, qb, 2211840);
  cvt_bf16_kernel<<<8640, 256, 0, stream>>>(t, tb, 2211840);
  gemm_f2f_kernel<<<dim3(32, 32), 576, 0, stream>>>(qb, tb, f2f);
  conv1_kernel<<<8192, 256, 0, stream>>>(f2f, w1, b1, x1);
  conv2_kernel<<<4096, 256, 0, stream>>>(x1, w2, b2, x2b);
  conv3_kernel<<<8192, 256, 0, stream>>>(x2b, w3, b3, x3);
  convf_kernel<<<128, 128, 0, stream>>>(x3, wf, bf, rowm);
  final_kernel<<<1, 128, 0, stream>>>(rowm, out);
}

// Round 2
// 737.157 us; speedup vs baseline: 1.3374x; 1.3374x over previous
//
#include <hip/hip_runtime.h>
#include <hip/hip_bf16.h>

typedef short short8 __attribute__((ext_vector_type(8)));
typedef float f32x4 __attribute__((ext_vector_type(4)));
typedef unsigned short ushort8_t __attribute__((ext_vector_type(8)));

#define AS3 __attribute__((address_space(3)))
#define AS1 __attribute__((address_space(1)))

__device__ __forceinline__ unsigned short f2bf(float f) {
  unsigned int u = __float_as_uint(f);
  u += 0x7FFFu + ((u >> 16) & 1u);   // round-to-nearest-even
  return (unsigned short)(u >> 16);
}

// ---------------- fp32 -> bf16 conversion (8 elems/thread) ----------------
__global__ __launch_bounds__(256) void cvt_bf16_kernel(const float* __restrict__ src,
                                                       unsigned short* __restrict__ dst,
                                                       int n8) {
  int idx = blockIdx.x * 256 + threadIdx.x;
  if (idx >= n8) return;
  const float4* s4 = (const float4*)src;
  float4 a = s4[2 * idx], b = s4[2 * idx + 1];
  ushort8_t o;
  o[0] = f2bf(a.x); o[1] = f2bf(a.y); o[2] = f2bf(a.z); o[3] = f2bf(a.w);
  o[4] = f2bf(b.x); o[5] = f2bf(b.y); o[6] = f2bf(b.z); o[7] = f2bf(b.w);
  ((ushort8_t*)dst)[idx] = o;
}

// ---------------- fused GEMM (bf16 MFMA) + max_p / mean_o -> f2f ----------------
// block: 576 threads = 9 waves in 3x3 grid; tile 144x144 (16 i-groups x 9 o, 16 j x 9 p)
// BK=32, single LDS buffer, global_load_lds width=16 staging (m97 structure).
__global__ __launch_bounds__(576) void gemm_f2f_kernel(const unsigned short* __restrict__ qb,
                                                       const unsigned short* __restrict__ tb,
                                                       float* __restrict__ f2f) {
  __shared__ __align__(16) char smem[36864];  // GEMM: A[144][32]@0 (9216B) B@9216; epilogue: scratch[48][144]@0, armax[144][16]@27648
  const int tid  = threadIdx.x;
  const int wv   = tid >> 6;
  const int lane = tid & 63;
  const int quad = lane >> 4;
  const int l16  = lane & 15;
  const int wr = wv / 3, wc = wv % 3;
  const int bi = blockIdx.y, bj = blockIdx.x;

  f32x4 acc[3][3];
#pragma unroll
  for (int a = 0; a < 3; ++a)
#pragma unroll
    for (int b = 0; b < 3; ++b) acc[a][b] = (f32x4){0.f, 0.f, 0.f, 0.f};

  const int arow = bi * 144 + wv * 16 + (lane >> 2);
  const int brow = bj * 144 + wv * 16 + (lane >> 2);
  const int kcol = (lane & 3) * 8;
  const unsigned short* gA = qb + (size_t)arow * 3840 + kcol;
  const unsigned short* gB = tb + (size_t)brow * 3840 + kcol;
  AS3 char* lA = (AS3 char*)smem + wv * 1024;
  AS3 char* lB = (AS3 char*)smem + 9216 + wv * 1024;
  const unsigned short* Al = (const unsigned short*)smem;
  const unsigned short* Bl = (const unsigned short*)(smem + 9216);

  for (int kt = 0; kt < 120; ++kt) {
    __syncthreads();
    __builtin_amdgcn_global_load_lds((const AS1 void*)(gA + kt * 32), (AS3 void*)lA, 16, 0, 0);
    __builtin_amdgcn_global_load_lds((const AS1 void*)(gB + kt * 32), (AS3 void*)lB, 16, 0, 0);
    __syncthreads();

    short8 a0 = *(const short8*)(Al + (wr * 48 +  0 + l16) * 32 + quad * 8);
    short8 a1 = *(const short8*)(Al + (wr * 48 + 16 + l16) * 32 + quad * 8);
    short8 a2 = *(const short8*)(Al + (wr * 48 + 32 + l16) * 32 + quad * 8);
#pragma unroll
    for (int sc = 0; sc < 3; ++sc) {
      short8 b = *(const short8*)(Bl + (wc * 48 + sc * 16 + l16) * 32 + quad * 8);
      acc[0][sc] = __builtin_amdgcn_mfma_f32_16x16x32_bf16(a0, b, acc[0][sc], 0, 0, 0);
      acc[1][sc] = __builtin_amdgcn_mfma_f32_16x16x32_bf16(a1, b, acc[1][sc], 0, 0, 0);
      acc[2][sc] = __builtin_amdgcn_mfma_f32_16x16x32_bf16(a2, b, acc[2][sc], 0, 0, 0);
    }
  }

  // -------- epilogue: 3 bands of 48 rows; rowmax over p, then mean over o --------
  __syncthreads();
  float* scratch = (float*)smem;            // [48][144]
  float* armax   = (float*)(smem + 27648);  // [144][16]
#pragma unroll 1
  for (int band = 0; band < 3; ++band) {
    if (wr == band) {
#pragma unroll
      for (int sr = 0; sr < 3; ++sr)
#pragma unroll
        for (int sc = 0; sc < 3; ++sc)
#pragma unroll
          for (int r = 0; r < 4; ++r)
            scratch[(sr * 16 + quad * 4 + r) * 144 + wc * 48 + sc * 16 + l16] = acc[sr][sc][r];
    }
    __syncthreads();
    for (int idx = tid; idx < 768; idx += 576) {
      int r = idx >> 4, j = idx & 15;
      const float* row = scratch + r * 144 + j * 9;
      float m = row[0];
#pragma unroll
      for (int p = 1; p < 9; ++p) m = fmaxf(m, row[p]);
      armax[(band * 48 + r) * 16 + j] = m;
    }
    __syncthreads();
  }
  if (tid < 256) {
    int i = tid >> 4, j = tid & 15;
    float s = 0.f;
#pragma unroll
    for (int o = 0; o < 9; ++o) s += armax[(i * 9 + o) * 16 + j];
    f2f[(bi * 16 + i) * 512 + bj * 16 + j] = s * (1.f / 9.f);
  }
}

// ---------------- conv1: 1->32ch 3x3 same + relu + 2x2 maxpool, 512^2 -> 256^2 ----------------
// LDS-tiled: one block = 32x32 pre-pool tile (16x16 post-pool), ALL 32 output channels.
__global__ __launch_bounds__(256) void conv1_kernel(const float* __restrict__ in,
                                                    const float* __restrict__ w1,
                                                    const float* __restrict__ b1,
                                                    float* __restrict__ out) {
  __shared__ float tile[34 * 36];
  int t = blockIdx.x;                 // 256 tiles (16x16 grid)
  int ty0 = (t >> 4) * 32, tx0 = (t & 15) * 32;
  int py = threadIdx.x >> 4, px = threadIdx.x & 15;

  for (int idx = threadIdx.x; idx < 34 * 34; idx += 256) {
    int r = idx / 34, c = idx % 34;
    int gy = ty0 + r - 1, gx = tx0 + c - 1;
    tile[r * 36 + c] = ((unsigned)gy < 512u && (unsigned)gx < 512u) ? in[gy * 512 + gx] : 0.f;
  }
  __syncthreads();

  float win[4][4];
#pragma unroll
  for (int r = 0; r < 4; ++r)
#pragma unroll
    for (int c = 0; c < 4; ++c)
      win[r][c] = tile[(2 * py + r) * 36 + 2 * px + c];

  int gy2 = (t >> 4) * 16 + py, gx2 = (t & 15) * 16 + px;
#pragma unroll 1
  for (int ch = 0; ch < 32; ++ch) {
    float w[9];
#pragma unroll
    for (int k = 0; k < 9; ++k) w[k] = w1[ch * 9 + k];
    float m = -INFINITY;
#pragma unroll
    for (int a = 0; a < 2; ++a)
#pragma unroll
      for (int b = 0; b < 2; ++b) {
        float s = 0.f;
#pragma unroll
        for (int ky = 0; ky < 3; ++ky)
#pragma unroll
          for (int kx = 0; kx < 3; ++kx) s += win[a + ky][b + kx] * w[ky * 3 + kx];
        m = fmaxf(m, s);
      }
    out[ch * 65536 + gy2 * 256 + gx2] = fmaxf(m + b1[ch], 0.f);
  }
}

// ---------------- conv2: 32->64ch 3x3 same + relu + 2x2 maxpool, 256^2 -> 128^2 ----------------
// LDS-tiled: block = 32x32 pre-pool tile x 8 output channels; stage each ci plane in LDS.
__global__ __launch_bounds__(256) void conv2_kernel(const float* __restrict__ in,
                                                    const float* __restrict__ w2,
                                                    const float* __restrict__ b2,
                                                    float* __restrict__ out) {
  __shared__ float tile[34 * 36];
  int cog = blockIdx.x >> 6;          // 0..7 -> 8 output channels each
  int t   = blockIdx.x & 63;          // 8x8 tiles over 256^2 pre-pool
  int ty0 = (t >> 3) * 32, tx0 = (t & 7) * 32;
  int py = threadIdx.x >> 4, px = threadIdx.x & 15;

  float acc[8][4];
#pragma unroll
  for (int co = 0; co < 8; ++co)
#pragma unroll
    for (int q = 0; q < 4; ++q) acc[co][q] = 0.f;

#pragma unroll 1
  for (int ci = 0; ci < 32; ++ci) {
    __syncthreads();
    const float* ip = in + ci * 65536;
    for (int idx = threadIdx.x; idx < 34 * 34; idx += 256) {
      int r = idx / 34, c = idx % 34;
      int gy = ty0 + r - 1, gx = tx0 + c - 1;
      tile[r * 36 + c] = ((unsigned)gy < 256u && (unsigned)gx < 256u) ? ip[gy * 256 + gx] : 0.f;
    }
    __syncthreads();

    float win[4][4];
#pragma unroll
    for (int r = 0; r < 4; ++r)
#pragma unroll
      for (int c = 0; c < 4; ++c)
        win[r][c] = tile[(2 * py + r) * 36 + 2 * px + c];

#pragma unroll
    for (int co = 0; co < 8; ++co) {
      const float* wp = w2 + ((cog * 8 + co) * 32 + ci) * 9;
      float w[9];
#pragma unroll
      for (int k = 0; k < 9; ++k) w[k] = wp[k];
#pragma unroll
      for (int a = 0; a < 2; ++a)
#pragma unroll
        for (int b = 0; b < 2; ++b) {
          float s = acc[co][a * 2 + b];
#pragma unroll
          for (int ky = 0; ky < 3; ++ky)
#pragma unroll
            for (int kx = 0; kx < 3; ++kx) s += win[a + ky][b + kx] * w[ky * 3 + kx];
          acc[co][a * 2 + b] = s;
        }
    }
  }

  int gy2 = (t >> 3) * 16 + py, gx2 = (t & 7) * 16 + px;
#pragma unroll
  for (int co = 0; co < 8; ++co) {
    float m = fmaxf(fmaxf(acc[co][0], acc[co][1]), fmaxf(acc[co][2], acc[co][3]));
    out[(cog * 8 + co) * 16384 + gy2 * 128 + gx2] = fmaxf(m + b2[cog * 8 + co], 0.f);
  }
}

// ---------------- conv3: 64->128ch 3x3 same + relu, 128^2 ----------------
// LDS-tiled: block = 16x16 tile x 16 output channels; stage 4 ci planes per barrier round.
__global__ __launch_bounds__(256) void conv3_kernel(const float* __restrict__ in,
                                                    const float* __restrict__ w3,
                                                    const float* __restrict__ b3,
                                                    float* __restrict__ out) {
  __shared__ float tile[4][18 * 20];
  int cog = blockIdx.x >> 6;          // 0..7 -> 16 output channels each
  int t   = blockIdx.x & 63;          // 8x8 tiles over 128^2
  int ty0 = (t >> 3) * 16, tx0 = (t & 7) * 16;
  int py = threadIdx.x >> 4, px = threadIdx.x & 15;

  float acc[16];
#pragma unroll
  for (int co = 0; co < 16; ++co) acc[co] = 0.f;

#pragma unroll 1
  for (int cb = 0; cb < 16; ++cb) {   // 4 input channels per round
    __syncthreads();
    for (int idx = threadIdx.x; idx < 4 * 324; idx += 256) {
      int pl = idx / 324, rc = idx % 324;
      int r = rc / 18, c = rc % 18;
      int gy = ty0 + r - 1, gx = tx0 + c - 1;
      tile[pl][r * 20 + c] = ((unsigned)gy < 128u && (unsigned)gx < 128u)
                                 ? in[(cb * 4 + pl) * 16384 + gy * 128 + gx] : 0.f;
    }
    __syncthreads();

#pragma unroll
    for (int pl = 0; pl < 4; ++pl) {
      float win[3][3];
#pragma unroll
      for (int r = 0; r < 3; ++r)
#pragma unroll
        for (int c = 0; c < 3; ++c)
          win[r][c] = tile[pl][(py + r) * 20 + px + c];
      int ci = cb * 4 + pl;
#pragma unroll
      for (int co = 0; co < 16; ++co) {
        const float* wp = w3 + ((cog * 16 + co) * 64 + ci) * 9;
        float s = acc[co];
#pragma unroll
        for (int ky = 0; ky < 3; ++ky)
#pragma unroll
          for (int kx = 0; kx < 3; ++kx) s += win[ky][kx] * wp[ky * 3 + kx];
        acc[co] = s;
      }
    }
  }

#pragma unroll
  for (int co = 0; co < 16; ++co)
    out[(cog * 16 + co) * 16384 + (ty0 + py) * 128 + tx0 + px] =
        fmaxf(acc[co] + b3[cog * 16 + co], 0.f);
}

// ---------------- 1x1 conv (128->1) + bias + clip + rowmax over x ----------------
__global__ __launch_bounds__(128) void convf_kernel(const float* __restrict__ in,
                                                    const float* __restrict__ wf,
                                                    const float* __restrict__ bfp,
                                                    float* __restrict__ rowm) {
  int y = blockIdx.x;
  int x = threadIdx.x;
  float acc = 0.f;
  for (int ci = 0; ci < 128; ++ci) acc += in[ci * 16384 + y * 128 + x] * wf[ci];
  float s = acc + bfp[0];
  s = fminf(fmaxf(s, -1.f), 1.f);
  for (int off = 32; off; off >>= 1) s = fmaxf(s, __shfl_down(s, off, 64));
  __shared__ float red[2];
  if ((x & 63) == 0) red[x >> 6] = s;
  __syncthreads();
  if (x == 0) rowm[y] = fmaxf(red[0], red[1]);
}

// ---------------- mean over rows -> scalar ----------------
__global__ __launch_bounds__(128) void final_kernel(const float* __restrict__ rowm,
                                                    float* __restrict__ out) {
  int x = threadIdx.x;
  float v = rowm[x];
  for (int off = 32; off; off >>= 1) v += __shfl_down(v, off, 64);
  __shared__ float red[2];
  if ((x & 63) == 0) red[x >> 6] = v;
  __syncthreads();
  if (x == 0) out[0] = (red[0] + red[1]) * (1.f / 128.f);
}

extern "C" void kernel_launch(void* const* d_in, const int* in_sizes, int n_in,
                              void* d_out, int out_size, void* d_ws, size_t ws_size,
                              hipStream_t stream) {
  const float* q  = (const float*)d_in[0];
  const float* t  = (const float*)d_in[1];
  const float* w1 = (const float*)d_in[2];
  const float* b1 = (const float*)d_in[3];
  const float* w2 = (const float*)d_in[4];
  const float* b2 = (const float*)d_in[5];
  const float* w3 = (const float*)d_in[6];
  const float* b3 = (const float*)d_in[7];
  const float* wf = (const float*)d_in[8];
  const float* bf = (const float*)d_in[9];
  float* out = (float*)d_out;
  char* ws = (char*)d_ws;

  unsigned short* qb  = (unsigned short*)(ws + 0);          // 35,389,440 B
  unsigned short* tb  = (unsigned short*)(ws + 35389440);   // 35,389,440 B
  float* f2f  = (float*)(ws + 70778880);                    // 512x512 f32
  float* x1   = (float*)(ws + 71827456);                    // 32x256x256
  float* x2b  = (float*)(ws + 80216064);                    // 64x128x128
  float* x3   = (float*)(ws + 84410368);                    // 128x128x128
  float* rowm = (float*)(ws + 92798976);                    // 128 f32

  cvt_bf16_kernel<<<8640, 256, 0, stream>>>(q, qb, 2211840);
  cvt_bf16_kernel<<<8640, 256, 0, stream>>>(t, tb, 2211840);
  gemm_f2f_kernel<<<dim3(32, 32), 576, 0, stream>>>(qb, tb, f2f);
  conv1_kernel<<<256, 256, 0, stream>>>(f2f, w1, b1, x1);
  conv2_kernel<<<512, 256, 0, stream>>>(x1, w2, b2, x2b);
  conv3_kernel<<<512, 256, 0, stream>>>(x2b, w3, b3, x3);
  convf_kernel<<<128, 128, 0, stream>>>(x3, wf, bf, rowm);
  final_kernel<<<1, 128, 0, stream>>>(rowm, out);
}

// Round 3
// 577.353 us; speedup vs baseline: 1.7075x; 1.2768x over previous
//
#include <hip/hip_runtime.h>
#include <hip/hip_bf16.h>

typedef float f32x4 __attribute__((ext_vector_type(4)));

#define AS3 __attribute__((address_space(3)))
#define AS1 __attribute__((address_space(1)))

// ---------------- fp32 -> fp8 e4m3 (OCP) conversion with x16 scale ----------------
// 16 elems/thread. n16 = total/16.
__global__ __launch_bounds__(256) void cvt_fp8_kernel(const float* __restrict__ src,
                                                      unsigned int* __restrict__ dst,
                                                      int n16) {
  int idx = blockIdx.x * 256 + threadIdx.x;
  if (idx >= n16) return;
  const float4* s4 = (const float4*)src;
  uint4 o;
  unsigned int* op = (unsigned int*)&o;
#pragma unroll
  for (int i = 0; i < 4; ++i) {
    float4 v = s4[idx * 4 + i];
    int w = 0;
    w = __builtin_amdgcn_cvt_pk_fp8_f32(v.x * 16.f, v.y * 16.f, w, false);
    w = __builtin_amdgcn_cvt_pk_fp8_f32(v.z * 16.f, v.w * 16.f, w, true);
    op[i] = w;
  }
  ((uint4*)dst)[idx] = o;
}

// ---------------- fused GEMM (fp8 MFMA) + max over p -> Cmax[4608][512] ----------------
// 288x288 tile, grid 16x16 = 256 blocks (1/CU). 768 thr = 12 waves in 6x2 grid,
// each wave 3x9 subtiles of 16x16 (48 rows x 144 cols). BK=64 bytes, 60 iters.
// Double-buffered LDS (2 x 36864B), one barrier per iter, global_load_lds width=16.
// LDS k-chunk XOR swizzle (^(row>>1)&3) -> 2-way (free) bank conflicts.
__global__ __launch_bounds__(768) void gemm_cmax_kernel(const unsigned char* __restrict__ qf8,
                                                        const unsigned char* __restrict__ tf8,
                                                        float* __restrict__ cmax) {
  __shared__ __align__(16) char smem[73728];
  const int tid  = threadIdx.x;
  const int wv   = tid >> 6;
  const int lane = tid & 63;
  const int quad = lane >> 4;
  const int l16  = lane & 15;
  const int wrow = wv >> 1, wcol = wv & 1;
  const int bi = blockIdx.y, bj = blockIdx.x;

  f32x4 acc[3][9];
#pragma unroll
  for (int a = 0; a < 3; ++a)
#pragma unroll
    for (int b = 0; b < 9; ++b) acc[a][b] = (f32x4){0.f, 0.f, 0.f, 0.f};

  // staging: 2304 16B chunks (A: 0..1151, B: 1152..2303), 3 rounds x 768 threads.
  // chunk c -> LDS offset c*16 (A tile [288][64] then B tile [288][64]).
  // global source applies the XOR swizzle so LDS slot (row, cl) holds global chunk cl^((row>>1)&3).
  const unsigned char* gptr[3];
#pragma unroll
  for (int r = 0; r < 3; ++r) {
    int c   = r * 768 + wv * 64 + lane;
    int mat = (c >= 1152);
    int cm  = c - mat * 1152;
    int row = cm >> 2, cl = cm & 3;
    int gch = cl ^ ((row >> 1) & 3);
    const unsigned char* base = mat ? (tf8 + (size_t)(bj * 288 + row) * 3840)
                                    : (qf8 + (size_t)(bi * 288 + row) * 3840);
    gptr[r] = base + gch * 16;
  }

  int buf = 0;
  // prologue: stage kt=0 into buf 0
#pragma unroll
  for (int r = 0; r < 3; ++r)
    __builtin_amdgcn_global_load_lds((const AS1 void*)(gptr[r]),
                                     (AS3 void*)(smem + (r * 768 + wv * 64) * 16), 16, 0, 0);

  const int arow0 = wrow * 48 + l16;
  const int bcol0 = wcol * 144 + l16;

  for (int kt = 0; kt < 60; ++kt) {
    __syncthreads();  // drains vmcnt: current buf ready; prev buf reads complete
    if (kt < 59) {
      int nb = buf ^ 1;
#pragma unroll
      for (int r = 0; r < 3; ++r)
        __builtin_amdgcn_global_load_lds((const AS1 void*)(gptr[r] + (kt + 1) * 64),
                                         (AS3 void*)(smem + nb * 36864 + (r * 768 + wv * 64) * 16),
                                         16, 0, 0);
    }
    const char* A = smem + buf * 36864;
    const char* B = A + 18432;
#pragma unroll
    for (int ks = 0; ks < 2; ++ks) {
      long av[3];
#pragma unroll
      for (int sr = 0; sr < 3; ++sr) {
        int row = arow0 + sr * 16;
        int ch  = ((ks * 2 + (quad >> 1)) ^ ((row >> 1) & 3));
        av[sr] = *(const long*)(A + row * 64 + ch * 16 + (quad & 1) * 8);
      }
#pragma unroll
      for (int c = 0; c < 9; ++c) {
        int col = bcol0 + c * 16;
        int ch  = ((ks * 2 + (quad >> 1)) ^ ((col >> 1) & 3));
        long bv = *(const long*)(B + col * 64 + ch * 16 + (quad & 1) * 8);
        acc[0][c] = __builtin_amdgcn_mfma_f32_16x16x32_fp8_fp8(av[0], bv, acc[0][c], 0, 0, 0);
        acc[1][c] = __builtin_amdgcn_mfma_f32_16x16x32_fp8_fp8(av[1], bv, acc[1][c], 0, 0, 0);
        acc[2][c] = __builtin_amdgcn_mfma_f32_16x16x32_fp8_fp8(av[2], bv, acc[2][c], 0, 0, 0);
      }
    }
    buf ^= 1;
  }

  // -------- epilogue: 18 bands of 16 rows; rowmax over each 9-col group --------
  __syncthreads();
  float* scr = (float*)smem;  // [16][288] = 18432 B
#pragma unroll
  for (int b = 0; b < 18; ++b) {
    const int bw = b / 3, bs = b - bw * 3;
    if (wrow == bw) {
#pragma unroll
      for (int c = 0; c < 9; ++c)
#pragma unroll
        for (int r = 0; r < 4; ++r)
          scr[(quad * 4 + r) * 288 + wcol * 144 + c * 16 + l16] = acc[bs][c][r] * (1.f / 256.f);
    }
    __syncthreads();
    if (tid < 512) {
      int row = tid >> 5, jg = tid & 31;
      const float* p = scr + row * 288 + jg * 9;
      float m = p[0];
#pragma unroll
      for (int k = 1; k < 9; ++k) m = fmaxf(m, p[k]);
      cmax[(size_t)(bi * 288 + b * 16 + row) * 512 + bj * 32 + jg] = m;
    }
    __syncthreads();
  }
}

// ---------------- mean over o (9 rows) -> f2f[512][512] ----------------
__global__ __launch_bounds__(512) void mean9_kernel(const float* __restrict__ cmax,
                                                    float* __restrict__ f2f) {
  int i = blockIdx.x, j = threadIdx.x;
  float s = 0.f;
#pragma unroll
  for (int o = 0; o < 9; ++o) s += cmax[(size_t)(i * 9 + o) * 512 + j];
  f2f[i * 512 + j] = s * (1.f / 9.f);
}

// ---------------- conv1: 1->32ch 3x3 same + relu + 2x2 maxpool, 512^2 -> 256^2 ----------------
__global__ __launch_bounds__(256) void conv1_kernel(const float* __restrict__ in,
                                                    const float* __restrict__ w1,
                                                    const float* __restrict__ b1,
                                                    float* __restrict__ out) {
  __shared__ float tile[34 * 36];
  int t = blockIdx.x;
  int ty0 = (t >> 4) * 32, tx0 = (t & 15) * 32;
  int py = threadIdx.x >> 4, px = threadIdx.x & 15;

  for (int idx = threadIdx.x; idx < 34 * 34; idx += 256) {
    int r = idx / 34, c = idx % 34;
    int gy = ty0 + r - 1, gx = tx0 + c - 1;
    tile[r * 36 + c] = ((unsigned)gy < 512u && (unsigned)gx < 512u) ? in[gy * 512 + gx] : 0.f;
  }
  __syncthreads();

  float win[4][4];
#pragma unroll
  for (int r = 0; r < 4; ++r)
#pragma unroll
    for (int c = 0; c < 4; ++c)
      win[r][c] = tile[(2 * py + r) * 36 + 2 * px + c];

  int gy2 = (t >> 4) * 16 + py, gx2 = (t & 15) * 16 + px;
#pragma unroll 1
  for (int ch = 0; ch < 32; ++ch) {
    float w[9];
#pragma unroll
    for (int k = 0; k < 9; ++k) w[k] = w1[ch * 9 + k];
    float m = -INFINITY;
#pragma unroll
    for (int a = 0; a < 2; ++a)
#pragma unroll
      for (int b = 0; b < 2; ++b) {
        float s = 0.f;
#pragma unroll
        for (int ky = 0; ky < 3; ++ky)
#pragma unroll
          for (int kx = 0; kx < 3; ++kx) s += win[a + ky][b + kx] * w[ky * 3 + kx];
        m = fmaxf(m, s);
      }
    out[ch * 65536 + gy2 * 256 + gx2] = fmaxf(m + b1[ch], 0.f);
  }
}

// ---------------- conv2: 32->64ch 3x3 same + relu + 2x2 maxpool, 256^2 -> 128^2 ----------------
__global__ __launch_bounds__(256) void conv2_kernel(const float* __restrict__ in,
                                                    const float* __restrict__ w2,
                                                    const float* __restrict__ b2,
                                                    float* __restrict__ out) {
  __shared__ float tile[34 * 36];
  int cog = blockIdx.x >> 6;
  int t   = blockIdx.x & 63;
  int ty0 = (t >> 3) * 32, tx0 = (t & 7) * 32;
  int py = threadIdx.x >> 4, px = threadIdx.x & 15;

  float acc[8][4];
#pragma unroll
  for (int co = 0; co < 8; ++co)
#pragma unroll
    for (int q = 0; q < 4; ++q) acc[co][q] = 0.f;

#pragma unroll 1
  for (int ci = 0; ci < 32; ++ci) {
    __syncthreads();
    const float* ip = in + ci * 65536;
    for (int idx = threadIdx.x; idx < 34 * 34; idx += 256) {
      int r = idx / 34, c = idx % 34;
      int gy = ty0 + r - 1, gx = tx0 + c - 1;
      tile[r * 36 + c] = ((unsigned)gy < 256u && (unsigned)gx < 256u) ? ip[gy * 256 + gx] : 0.f;
    }
    __syncthreads();

    float win[4][4];
#pragma unroll
    for (int r = 0; r < 4; ++r)
#pragma unroll
      for (int c = 0; c < 4; ++c)
        win[r][c] = tile[(2 * py + r) * 36 + 2 * px + c];

#pragma unroll
    for (int co = 0; co < 8; ++co) {
      const float* wp = w2 + ((cog * 8 + co) * 32 + ci) * 9;
      float w[9];
#pragma unroll
      for (int k = 0; k < 9; ++k) w[k] = wp[k];
#pragma unroll
      for (int a = 0; a < 2; ++a)
#pragma unroll
        for (int b = 0; b < 2; ++b) {
          float s = acc[co][a * 2 + b];
#pragma unroll
          for (int ky = 0; ky < 3; ++ky)
#pragma unroll
            for (int kx = 0; kx < 3; ++kx) s += win[a + ky][b + kx] * w[ky * 3 + kx];
          acc[co][a * 2 + b] = s;
        }
    }
  }

  int gy2 = (t >> 3) * 16 + py, gx2 = (t & 7) * 16 + px;
#pragma unroll
  for (int co = 0; co < 8; ++co) {
    float m = fmaxf(fmaxf(acc[co][0], acc[co][1]), fmaxf(acc[co][2], acc[co][3]));
    out[(cog * 8 + co) * 16384 + gy2 * 128 + gx2] = fmaxf(m + b2[cog * 8 + co], 0.f);
  }
}

// ---------------- conv3: 64->128ch 3x3 same + relu, 128^2 ----------------
__global__ __launch_bounds__(256) void conv3_kernel(const float* __restrict__ in,
                                                    const float* __restrict__ w3,
                                                    const float* __restrict__ b3,
                                                    float* __restrict__ out) {
  __shared__ float tile[4][18 * 20];
  int cog = blockIdx.x >> 6;
  int t   = blockIdx.x & 63;
  int ty0 = (t >> 3) * 16, tx0 = (t & 7) * 16;
  int py = threadIdx.x >> 4, px = threadIdx.x & 15;

  float acc[16];
#pragma unroll
  for (int co = 0; co < 16; ++co) acc[co] = 0.f;

#pragma unroll 1
  for (int cb = 0; cb < 16; ++cb) {
    __syncthreads();
    for (int idx = threadIdx.x; idx < 4 * 324; idx += 256) {
      int pl = idx / 324, rc = idx % 324;
      int r = rc / 18, c = rc % 18;
      int gy = ty0 + r - 1, gx = tx0 + c - 1;
      tile[pl][r * 20 + c] = ((unsigned)gy < 128u && (unsigned)gx < 128u)
                                 ? in[(cb * 4 + pl) * 16384 + gy * 128 + gx] : 0.f;
    }
    __syncthreads();

#pragma unroll
    for (int pl = 0; pl < 4; ++pl) {
      float win[3][3];
#pragma unroll
      for (int r = 0; r < 3; ++r)
#pragma unroll
        for (int c = 0; c < 3; ++c)
          win[r][c] = tile[pl][(py + r) * 20 + px + c];
      int ci = cb * 4 + pl;
#pragma unroll
      for (int co = 0; co < 16; ++co) {
        const float* wp = w3 + ((cog * 16 + co) * 64 + ci) * 9;
        float s = acc[co];
#pragma unroll
        for (int ky = 0; ky < 3; ++ky)
#pragma unroll
          for (int kx = 0; kx < 3; ++kx) s += win[ky][kx] * wp[ky * 3 + kx];
        acc[co] = s;
      }
    }
  }

#pragma unroll
  for (int co = 0; co < 16; ++co)
    out[(cog * 16 + co) * 16384 + (ty0 + py) * 128 + tx0 + px] =
        fmaxf(acc[co] + b3[cog * 16 + co], 0.f);
}

// ---------------- 1x1 conv (128->1) + bias + clip + rowmax over x ----------------
__global__ __launch_bounds__(512) void convf_kernel(const float* __restrict__ in,
                                                    const float* __restrict__ wf,
                                                    const float* __restrict__ bfp,
                                                    float* __restrict__ rowm) {
  __shared__ float part[512];
  int y = blockIdx.x, tid = threadIdx.x;
  int pt = tid >> 7, x = tid & 127;
  float acc = 0.f;
  const float* ip = in + y * 128 + x;
  for (int ci = pt * 32; ci < pt * 32 + 32; ++ci) acc += ip[ci * 16384] * wf[ci];
  part[tid] = acc;
  __syncthreads();
  if (tid < 128) {
    float s = part[tid] + part[tid + 128] + part[tid + 256] + part[tid + 384] + bfp[0];
    part[tid] = fminf(fmaxf(s, -1.f), 1.f);
  }
  __syncthreads();
  if (tid < 64) {
    float m = fmaxf(part[tid], part[tid + 64]);
    for (int off = 32; off; off >>= 1) m = fmaxf(m, __shfl_down(m, off, 64));
    if (tid == 0) rowm[y] = m;
  }
}

// ---------------- mean over rows -> scalar ----------------
__global__ __launch_bounds__(128) void final_kernel(const float* __restrict__ rowm,
                                                    float* __restrict__ out) {
  int x = threadIdx.x;
  float v = rowm[x];
  for (int off = 32; off; off >>= 1) v += __shfl_down(v, off, 64);
  __shared__ float red[2];
  if ((x & 63) == 0) red[x >> 6] = v;
  __syncthreads();
  if (x == 0) out[0] = (red[0] + red[1]) * (1.f / 128.f);
}

extern "C" void kernel_launch(void* const* d_in, const int* in_sizes, int n_in,
                              void* d_out, int out_size, void* d_ws, size_t ws_size,
                              hipStream_t stream) {
  const float* q  = (const float*)d_in[0];
  const float* t  = (const float*)d_in[1];
  const float* w1 = (const float*)d_in[2];
  const float* b1 = (const float*)d_in[3];
  const float* w2 = (const float*)d_in[4];
  const float* b2 = (const float*)d_in[5];
  const float* w3 = (const float*)d_in[6];
  const float* b3 = (const float*)d_in[7];
  const float* wf = (const float*)d_in[8];
  const float* bf = (const float*)d_in[9];
  float* out = (float*)d_out;
  char* ws = (char*)d_ws;

  // workspace layout (bytes)
  unsigned char* qf8 = (unsigned char*)(ws + 0);          // 4608x3840 fp8 = 17,694,720
  unsigned char* tf8 = (unsigned char*)(ws + 17694720);   // 17,694,720
  float* cmax = (float*)(ws + 35389440);                  // 4608x512 f32 = 9,437,184
  float* f2f  = (float*)(ws + 44826624);                  // 512x512 f32
  float* x1   = (float*)(ws + 45875200);                  // 32x256x256
  float* x2b  = (float*)(ws + 54263808);                  // 64x128x128
  float* x3   = (float*)(ws + 58458112);                  // 128x128x128
  float* rowm = (float*)(ws + 66846720);                  // 128 f32

  cvt_fp8_kernel<<<4320, 256, 0, stream>>>(q, (unsigned int*)qf8, 1105920);
  cvt_fp8_kernel<<<4320, 256, 0, stream>>>(t, (unsigned int*)tf8, 1105920);
  gemm_cmax_kernel<<<dim3(16, 16), 768, 0, stream>>>(qf8, tf8, cmax);
  mean9_kernel<<<512, 512, 0, stream>>>(cmax, f2f);
  conv1_kernel<<<256, 256, 0, stream>>>(f2f, w1, b1, x1);
  conv2_kernel<<<512, 256, 0, stream>>>(x1, w2, b2, x2b);
  conv3_kernel<<<512, 256, 0, stream>>>(x2b, w3, b3, x3);
  convf_kernel<<<128, 512, 0, stream>>>(x3, wf, bf, rowm);
  final_kernel<<<1, 128, 0, stream>>>(rowm, out);
}

// Round 4
// 461.147 us; speedup vs baseline: 2.1378x; 1.2520x over previous
//
#include <hip/hip_runtime.h>
#include <hip/hip_bf16.h>

typedef float f32x4 __attribute__((ext_vector_type(4)));

#define AS3 __attribute__((address_space(3)))
#define AS1 __attribute__((address_space(1)))

// ---------------- fp32 -> fp8 e4m3 (OCP) conversion with x16 scale ----------------
__global__ __launch_bounds__(256) void cvt_fp8_kernel(const float* __restrict__ src,
                                                      unsigned int* __restrict__ dst,
                                                      int n16) {
  int idx = blockIdx.x * 256 + threadIdx.x;
  if (idx >= n16) return;
  const float4* s4 = (const float4*)src;
  uint4 o;
  unsigned int* op = (unsigned int*)&o;
#pragma unroll
  for (int i = 0; i < 4; ++i) {
    float4 v = s4[idx * 4 + i];
    int w = 0;
    w = __builtin_amdgcn_cvt_pk_fp8_f32(v.x * 16.f, v.y * 16.f, w, false);
    w = __builtin_amdgcn_cvt_pk_fp8_f32(v.z * 16.f, v.w * 16.f, w, true);
    op[i] = w;
  }
  ((uint4*)dst)[idx] = o;
}

// ---------------- fused GEMM (fp8 MFMA) + max over p -> Cmax[4608][512] ----------------
__global__ __launch_bounds__(768) void gemm_cmax_kernel(const unsigned char* __restrict__ qf8,
                                                        const unsigned char* __restrict__ tf8,
                                                        float* __restrict__ cmax) {
  __shared__ __align__(16) char smem[73728];
  const int tid  = threadIdx.x;
  const int wv   = tid >> 6;
  const int lane = tid & 63;
  const int quad = lane >> 4;
  const int l16  = lane & 15;
  const int wrow = wv >> 1, wcol = wv & 1;
  const int bi = blockIdx.y, bj = blockIdx.x;

  f32x4 acc[3][9];
#pragma unroll
  for (int a = 0; a < 3; ++a)
#pragma unroll
    for (int b = 0; b < 9; ++b) acc[a][b] = (f32x4){0.f, 0.f, 0.f, 0.f};

  const unsigned char* gptr[3];
#pragma unroll
  for (int r = 0; r < 3; ++r) {
    int c   = r * 768 + wv * 64 + lane;
    int mat = (c >= 1152);
    int cm  = c - mat * 1152;
    int row = cm >> 2, cl = cm & 3;
    int gch = cl ^ ((row >> 1) & 3);
    const unsigned char* base = mat ? (tf8 + (size_t)(bj * 288 + row) * 3840)
                                    : (qf8 + (size_t)(bi * 288 + row) * 3840);
    gptr[r] = base + gch * 16;
  }

  int buf = 0;
#pragma unroll
  for (int r = 0; r < 3; ++r)
    __builtin_amdgcn_global_load_lds((const AS1 void*)(gptr[r]),
                                     (AS3 void*)(smem + (r * 768 + wv * 64) * 16), 16, 0, 0);

  const int arow0 = wrow * 48 + l16;
  const int bcol0 = wcol * 144 + l16;

  for (int kt = 0; kt < 60; ++kt) {
    __syncthreads();
    if (kt < 59) {
      int nb = buf ^ 1;
#pragma unroll
      for (int r = 0; r < 3; ++r)
        __builtin_amdgcn_global_load_lds((const AS1 void*)(gptr[r] + (kt + 1) * 64),
                                         (AS3 void*)(smem + nb * 36864 + (r * 768 + wv * 64) * 16),
                                         16, 0, 0);
    }
    const char* A = smem + buf * 36864;
    const char* B = A + 18432;
#pragma unroll
    for (int ks = 0; ks < 2; ++ks) {
      long av[3];
#pragma unroll
      for (int sr = 0; sr < 3; ++sr) {
        int row = arow0 + sr * 16;
        int ch  = ((ks * 2 + (quad >> 1)) ^ ((row >> 1) & 3));
        av[sr] = *(const long*)(A + row * 64 + ch * 16 + (quad & 1) * 8);
      }
#pragma unroll
      for (int c = 0; c < 9; ++c) {
        int col = bcol0 + c * 16;
        int ch  = ((ks * 2 + (quad >> 1)) ^ ((col >> 1) & 3));
        long bv = *(const long*)(B + col * 64 + ch * 16 + (quad & 1) * 8);
        acc[0][c] = __builtin_amdgcn_mfma_f32_16x16x32_fp8_fp8(av[0], bv, acc[0][c], 0, 0, 0);
        acc[1][c] = __builtin_amdgcn_mfma_f32_16x16x32_fp8_fp8(av[1], bv, acc[1][c], 0, 0, 0);
        acc[2][c] = __builtin_amdgcn_mfma_f32_16x16x32_fp8_fp8(av[2], bv, acc[2][c], 0, 0, 0);
      }
    }
    buf ^= 1;
  }

  __syncthreads();
  float* scr = (float*)smem;  // [16][288]
#pragma unroll
  for (int b = 0; b < 18; ++b) {
    const int bw = b / 3, bs = b - bw * 3;
    if (wrow == bw) {
#pragma unroll
      for (int c = 0; c < 9; ++c)
#pragma unroll
        for (int r = 0; r < 4; ++r)
          scr[(quad * 4 + r) * 288 + wcol * 144 + c * 16 + l16] = acc[bs][c][r] * (1.f / 256.f);
    }
    __syncthreads();
    if (tid < 512) {
      int row = tid >> 5, jg = tid & 31;
      const float* p = scr + row * 288 + jg * 9;
      float m = p[0];
#pragma unroll
      for (int k = 1; k < 9; ++k) m = fmaxf(m, p[k]);
      cmax[(size_t)(bi * 288 + b * 16 + row) * 512 + bj * 32 + jg] = m;
    }
    __syncthreads();
  }
}

// ---------------- mean over o (9 rows) -> f2f[512][512] ----------------
__global__ __launch_bounds__(512) void mean9_kernel(const float* __restrict__ cmax,
                                                    float* __restrict__ f2f) {
  int i = blockIdx.x, j = threadIdx.x;
  float s = 0.f;
#pragma unroll
  for (int o = 0; o < 9; ++o) s += cmax[(size_t)(i * 9 + o) * 512 + j];
  f2f[i * 512 + j] = s * (1.f / 9.f);
}

// ---------------- conv1: 1->32ch 3x3 same + relu + 2x2 maxpool, 512^2 -> 256^2 ----------------
__global__ __launch_bounds__(256) void conv1_kernel(const float* __restrict__ in,
                                                    const float* __restrict__ w1,
                                                    const float* __restrict__ b1,
                                                    float* __restrict__ out) {
  __shared__ float tile[34 * 36];
  __shared__ float wl[320];
  int t = blockIdx.x;
  int ty0 = (t >> 4) * 32, tx0 = (t & 15) * 32;
  int py = threadIdx.x >> 4, px = threadIdx.x & 15;

  for (int idx = threadIdx.x; idx < 320; idx += 256)
    wl[idx] = (idx < 288) ? w1[idx] : b1[idx - 288];
  for (int idx = threadIdx.x; idx < 34 * 34; idx += 256) {
    int r = idx / 34, c = idx % 34;
    int gy = ty0 + r - 1, gx = tx0 + c - 1;
    tile[r * 36 + c] = ((unsigned)gy < 512u && (unsigned)gx < 512u) ? in[gy * 512 + gx] : 0.f;
  }
  __syncthreads();

  float win[4][4];
#pragma unroll
  for (int r = 0; r < 4; ++r)
#pragma unroll
    for (int c = 0; c < 4; ++c)
      win[r][c] = tile[(2 * py + r) * 36 + 2 * px + c];

  int gy2 = (t >> 4) * 16 + py, gx2 = (t & 15) * 16 + px;
#pragma unroll 1
  for (int ch = 0; ch < 32; ++ch) {
    float w[9];
#pragma unroll
    for (int k = 0; k < 9; ++k) w[k] = wl[ch * 9 + k];
    float m = -INFINITY;
#pragma unroll
    for (int a = 0; a < 2; ++a)
#pragma unroll
      for (int b = 0; b < 2; ++b) {
        float s = 0.f;
#pragma unroll
        for (int ky = 0; ky < 3; ++ky)
#pragma unroll
          for (int kx = 0; kx < 3; ++kx) s += win[a + ky][b + kx] * w[ky * 3 + kx];
        m = fmaxf(m, s);
      }
    out[ch * 65536 + gy2 * 256 + gx2] = fmaxf(m + wl[288 + ch], 0.f);
  }
}

// ---------------- conv2: 32->64ch 3x3 same + relu + 2x2 maxpool, 256^2 -> 128^2 ----------------
// Weights in LDS (stride-12, b128 reads). Input double-buffered, 2 ci planes/round,
// register-prefetch software pipeline, 1 barrier/round. 8 co per block.
__global__ __launch_bounds__(256) void conv2_kernel(const float* __restrict__ in,
                                                    const float* __restrict__ w2,
                                                    const float* __restrict__ b2,
                                                    float* __restrict__ out) {
  __shared__ __align__(16) float wlds[32 * 8 * 12];   // [ci][co][12] = 12288 B
  __shared__ float tile[2][2][34 * 36];               // [buf][pl] = 19584 B
  const int tid = threadIdx.x;
  int cog = blockIdx.x >> 6;          // 0..7 -> 8 output channels
  int t   = blockIdx.x & 63;          // 8x8 tiles of 32x32 pre-pool
  int ty0 = (t >> 3) * 32, tx0 = (t & 7) * 32;
  int py = tid >> 4, px = tid & 15;

  // stage weights: 8 co x 32 ci x 9
  for (int idx = tid; idx < 2304; idx += 256) {
    int co = idx / 288, rem = idx % 288, ci = rem / 9, k = rem % 9;
    wlds[(ci * 8 + co) * 12 + k] = w2[((cog * 8 + co) * 32 + ci) * 9 + k];
  }
  // prologue: stage ci group 0 (planes 0,1)
  for (int idx = tid; idx < 2312; idx += 256) {
    int pl = idx / 1156, rc = idx % 1156, r = rc / 34, c = rc % 34;
    int gy = ty0 + r - 1, gx = tx0 + c - 1;
    tile[0][pl][r * 36 + c] = ((unsigned)gy < 256u && (unsigned)gx < 256u)
                                  ? in[pl * 65536 + gy * 256 + gx] : 0.f;
  }
  __syncthreads();

  float acc[4][8];
#pragma unroll
  for (int p = 0; p < 4; ++p)
#pragma unroll
    for (int co = 0; co < 8; ++co) acc[p][co] = 0.f;

#pragma unroll 1
  for (int cb = 0; cb < 16; ++cb) {
    int buf = cb & 1;
    // prefetch next group into registers
    float pf[10];
    if (cb < 15) {
#pragma unroll
      for (int i = 0; i < 10; ++i) {
        int idx = tid + i * 256;
        float v = 0.f;
        if (idx < 2312) {
          int pl = idx / 1156, rc = idx % 1156, r = rc / 34, c = rc % 34;
          int gy = ty0 + r - 1, gx = tx0 + c - 1;
          if ((unsigned)gy < 256u && (unsigned)gx < 256u)
            v = in[((cb + 1) * 2 + pl) * 65536 + gy * 256 + gx];
        }
        pf[i] = v;
      }
    }
    // compute current buffer
#pragma unroll
    for (int pl = 0; pl < 2; ++pl) {
      float win[4][4];
#pragma unroll
      for (int r = 0; r < 4; ++r) {
        float2 lo = *(const float2*)&tile[buf][pl][(2 * py + r) * 36 + 2 * px];
        float2 hi = *(const float2*)&tile[buf][pl][(2 * py + r) * 36 + 2 * px + 2];
        win[r][0] = lo.x; win[r][1] = lo.y; win[r][2] = hi.x; win[r][3] = hi.y;
      }
      int ci = cb * 2 + pl;
#pragma unroll
      for (int co = 0; co < 8; ++co) {
        const float* wp = &wlds[(ci * 8 + co) * 12];
        float4 w0 = *(const float4*)wp;
        float4 w1v = *(const float4*)(wp + 4);
        float w8 = wp[8];
        float w[9] = {w0.x, w0.y, w0.z, w0.w, w1v.x, w1v.y, w1v.z, w1v.w, w8};
#pragma unroll
        for (int a = 0; a < 2; ++a)
#pragma unroll
          for (int b = 0; b < 2; ++b) {
            float s = acc[a * 2 + b][co];
#pragma unroll
            for (int ky = 0; ky < 3; ++ky)
#pragma unroll
              for (int kx = 0; kx < 3; ++kx) s += win[a + ky][b + kx] * w[ky * 3 + kx];
            acc[a * 2 + b][co] = s;
          }
      }
    }
    // write prefetched group to other buffer
    if (cb < 15) {
#pragma unroll
      for (int i = 0; i < 10; ++i) {
        int idx = tid + i * 256;
        if (idx < 2312) {
          int pl = idx / 1156, rc = idx % 1156, r = rc / 34, c = rc % 34;
          tile[buf ^ 1][pl][r * 36 + c] = pf[i];
        }
      }
    }
    __syncthreads();
  }

  int gy2 = (t >> 3) * 16 + py, gx2 = (t & 7) * 16 + px;
#pragma unroll
  for (int co = 0; co < 8; ++co) {
    float m = fmaxf(fmaxf(acc[0][co], acc[1][co]), fmaxf(acc[2][co], acc[3][co]));
    out[(cog * 8 + co) * 16384 + gy2 * 128 + gx2] = fmaxf(m + b2[cog * 8 + co], 0.f);
  }
}

// ---------------- conv3: 64->128ch 3x3 same + relu, 128^2 ----------------
// Weights in LDS; 4 ci planes/round, double-buffered + register prefetch;
// 2 output px per thread (32x16 tile), 8 co per block.
__global__ __launch_bounds__(256) void conv3_kernel(const float* __restrict__ in,
                                                    const float* __restrict__ w3,
                                                    const float* __restrict__ b3,
                                                    float* __restrict__ out) {
  __shared__ __align__(16) float wlds[64 * 8 * 12];   // 24576 B
  __shared__ float tile[2][4][18 * 40];               // stride 40 (2-way banks) = 23040 B
  const int tid = threadIdx.x;
  int cog = blockIdx.x >> 5;          // 0..15 -> 8 output channels
  int t   = blockIdx.x & 31;          // 8 (y) x 4 (x) tiles of 16x32
  int ty0 = (t >> 2) * 16, tx0 = (t & 3) * 32;
  int py = tid >> 4, px = tid & 15;

  for (int idx = tid; idx < 4608; idx += 256) {
    int co = idx / 576, rem = idx % 576, ci = rem / 9, k = rem % 9;
    wlds[(ci * 8 + co) * 12 + k] = w3[((cog * 8 + co) * 64 + ci) * 9 + k];
  }
  for (int idx = tid; idx < 2448; idx += 256) {
    int pl = idx / 612, rc = idx % 612, r = rc / 34, c = rc % 34;
    int gy = ty0 + r - 1, gx = tx0 + c - 1;
    tile[0][pl][r * 40 + c] = ((unsigned)gy < 128u && (unsigned)gx < 128u)
                                  ? in[pl * 16384 + gy * 128 + gx] : 0.f;
  }
  __syncthreads();

  float acc[2][8];
#pragma unroll
  for (int p = 0; p < 2; ++p)
#pragma unroll
    for (int co = 0; co < 8; ++co) acc[p][co] = 0.f;

#pragma unroll 1
  for (int cb = 0; cb < 16; ++cb) {
    int buf = cb & 1;
    float pf[10];
    if (cb < 15) {
#pragma unroll
      for (int i = 0; i < 10; ++i) {
        int idx = tid + i * 256;
        float v = 0.f;
        if (idx < 2448) {
          int pl = idx / 612, rc = idx % 612, r = rc / 34, c = rc % 34;
          int gy = ty0 + r - 1, gx = tx0 + c - 1;
          if ((unsigned)gy < 128u && (unsigned)gx < 128u)
            v = in[((cb + 1) * 4 + pl) * 16384 + gy * 128 + gx];
        }
        pf[i] = v;
      }
    }
#pragma unroll
    for (int pl = 0; pl < 4; ++pl) {
      float win[3][6];
#pragma unroll
      for (int r = 0; r < 3; ++r) {
#pragma unroll
        for (int c = 0; c < 3; ++c) {
          win[r][c]     = tile[buf][pl][(py + r) * 40 + px + c];
          win[r][3 + c] = tile[buf][pl][(py + r) * 40 + px + 16 + c];
        }
      }
      int ci = cb * 4 + pl;
#pragma unroll
      for (int co = 0; co < 8; ++co) {
        const float* wp = &wlds[(ci * 8 + co) * 12];
        float4 w0 = *(const float4*)wp;
        float4 w1v = *(const float4*)(wp + 4);
        float w8 = wp[8];
        float w[9] = {w0.x, w0.y, w0.z, w0.w, w1v.x, w1v.y, w1v.z, w1v.w, w8};
        float s0 = acc[0][co], s1 = acc[1][co];
#pragma unroll
        for (int ky = 0; ky < 3; ++ky)
#pragma unroll
          for (int kx = 0; kx < 3; ++kx) {
            s0 += win[ky][kx] * w[ky * 3 + kx];
            s1 += win[ky][3 + kx] * w[ky * 3 + kx];
          }
        acc[0][co] = s0; acc[1][co] = s1;
      }
    }
    if (cb < 15) {
#pragma unroll
      for (int i = 0; i < 10; ++i) {
        int idx = tid + i * 256;
        if (idx < 2448) {
          int pl = idx / 612, rc = idx % 612, r = rc / 34, c = rc % 34;
          tile[buf ^ 1][pl][r * 40 + c] = pf[i];
        }
      }
    }
    __syncthreads();
  }

  int y = ty0 + py;
#pragma unroll
  for (int co = 0; co < 8; ++co) {
    float bias = b3[cog * 8 + co];
    out[(cog * 8 + co) * 16384 + y * 128 + tx0 + px]      = fmaxf(acc[0][co] + bias, 0.f);
    out[(cog * 8 + co) * 16384 + y * 128 + tx0 + px + 16] = fmaxf(acc[1][co] + bias, 0.f);
  }
}

// ---------------- 1x1 conv (128->1) + bias + clip + rowmax over x ----------------
__global__ __launch_bounds__(512) void convf_kernel(const float* __restrict__ in,
                                                    const float* __restrict__ wf,
                                                    const float* __restrict__ bfp,
                                                    float* __restrict__ rowm) {
  __shared__ float part[512];
  int y = blockIdx.x, tid = threadIdx.x;
  int pt = tid >> 7, x = tid & 127;
  float acc = 0.f;
  const float* ip = in + y * 128 + x;
  for (int ci = pt * 32; ci < pt * 32 + 32; ++ci) acc += ip[ci * 16384] * wf[ci];
  part[tid] = acc;
  __syncthreads();
  if (tid < 128) {
    float s = part[tid] + part[tid + 128] + part[tid + 256] + part[tid + 384] + bfp[0];
    part[tid] = fminf(fmaxf(s, -1.f), 1.f);
  }
  __syncthreads();
  if (tid < 64) {
    float m = fmaxf(part[tid], part[tid + 64]);
    for (int off = 32; off; off >>= 1) m = fmaxf(m, __shfl_down(m, off, 64));
    if (tid == 0) rowm[y] = m;
  }
}

// ---------------- mean over rows -> scalar ----------------
__global__ __launch_bounds__(128) void final_kernel(const float* __restrict__ rowm,
                                                    float* __restrict__ out) {
  int x = threadIdx.x;
  float v = rowm[x];
  for (int off = 32; off; off >>= 1) v += __shfl_down(v, off, 64);
  __shared__ float red[2];
  if ((x & 63) == 0) red[x >> 6] = v;
  __syncthreads();
  if (x == 0) out[0] = (red[0] + red[1]) * (1.f / 128.f);
}

extern "C" void kernel_launch(void* const* d_in, const int* in_sizes, int n_in,
                              void* d_out, int out_size, void* d_ws, size_t ws_size,
                              hipStream_t stream) {
  const float* q  = (const float*)d_in[0];
  const float* t  = (const float*)d_in[1];
  const float* w1 = (const float*)d_in[2];
  const float* b1 = (const float*)d_in[3];
  const float* w2 = (const float*)d_in[4];
  const float* b2 = (const float*)d_in[5];
  const float* w3 = (const float*)d_in[6];
  const float* b3 = (const float*)d_in[7];
  const float* wf = (const float*)d_in[8];
  const float* bf = (const float*)d_in[9];
  float* out = (float*)d_out;
  char* ws = (char*)d_ws;

  unsigned char* qf8 = (unsigned char*)(ws + 0);          // 17,694,720
  unsigned char* tf8 = (unsigned char*)(ws + 17694720);   // 17,694,720
  float* cmax = (float*)(ws + 35389440);                  // 9,437,184
  float* f2f  = (float*)(ws + 44826624);                  // 512x512
  float* x1   = (float*)(ws + 45875200);                  // 32x256x256
  float* x2b  = (float*)(ws + 54263808);                  // 64x128x128
  float* x3   = (float*)(ws + 58458112);                  // 128x128x128
  float* rowm = (float*)(ws + 66846720);                  // 128

  cvt_fp8_kernel<<<4320, 256, 0, stream>>>(q, (unsigned int*)qf8, 1105920);
  cvt_fp8_kernel<<<4320, 256, 0, stream>>>(t, (unsigned int*)tf8, 1105920);
  gemm_cmax_kernel<<<dim3(16, 16), 768, 0, stream>>>(qf8, tf8, cmax);
  mean9_kernel<<<512, 512, 0, stream>>>(cmax, f2f);
  conv1_kernel<<<256, 256, 0, stream>>>(f2f, w1, b1, x1);
  conv2_kernel<<<512, 256, 0, stream>>>(x1, w2, b2, x2b);
  conv3_kernel<<<512, 256, 0, stream>>>(x2b, w3, b3, x3);
  convf_kernel<<<128, 512, 0, stream>>>(x3, wf, bf, rowm);
  final_kernel<<<1, 128, 0, stream>>>(rowm, out);
}

// Round 5
// 444.378 us; speedup vs baseline: 2.2185x; 1.0377x over previous
//
#include <hip/hip_runtime.h>
#include <hip/hip_bf16.h>

typedef float f32x4 __attribute__((ext_vector_type(4)));
typedef int v8i __attribute__((ext_vector_type(8)));

#define AS3 __attribute__((address_space(3)))
#define AS1 __attribute__((address_space(1)))

// ---------------- fp32 -> fp8 e4m3 (OCP) conversion with x16 scale ----------------
__global__ __launch_bounds__(256) void cvt_fp8_kernel(const float* __restrict__ src,
                                                      unsigned int* __restrict__ dst,
                                                      int n16) {
  int idx = blockIdx.x * 256 + threadIdx.x;
  if (idx >= n16) return;
  const float4* s4 = (const float4*)src;
  uint4 o;
  unsigned int* op = (unsigned int*)&o;
#pragma unroll
  for (int i = 0; i < 4; ++i) {
    float4 v = s4[idx * 4 + i];
    int w = 0;
    w = __builtin_amdgcn_cvt_pk_fp8_f32(v.x * 16.f, v.y * 16.f, w, false);
    w = __builtin_amdgcn_cvt_pk_fp8_f32(v.z * 16.f, v.w * 16.f, w, true);
    op[i] = w;
  }
  ((uint4*)dst)[idx] = o;
}

// ---------------- fused GEMM (MX fp8, K=128) + max over p -> Cmax[4608][512] ----------------
// 288x288 tile, grid 16x16 = 256 blocks (1/CU). 768 thr = 12 waves (6x2).
// BK=128 bytes, 30 iters, double-buffered LDS (2 x 73728 B), global_load_lds w=16.
// LDS: A[288][128] @0, B[288][128] @36864 per buffer; 16B-chunk XOR swizzle ^(row&7).
__global__ __launch_bounds__(768) void gemm_cmax_kernel(const unsigned char* __restrict__ qf8,
                                                        const unsigned char* __restrict__ tf8,
                                                        float* __restrict__ cmax) {
  __shared__ __align__(16) char smem[147456];
  const int tid  = threadIdx.x;
  const int wv   = tid >> 6;
  const int lane = tid & 63;
  const int quad = lane >> 4;
  const int l16  = lane & 15;
  const int wrow = wv >> 1, wcol = wv & 1;
  const int bi = blockIdx.y, bj = blockIdx.x;

  f32x4 acc[3][9];
#pragma unroll
  for (int a = 0; a < 3; ++a)
#pragma unroll
    for (int b = 0; b < 9; ++b) acc[a][b] = (f32x4){0.f, 0.f, 0.f, 0.f};

  // staging map: slot s in [0,4608): A = s<2304 (row=s>>3, chunk pc=s&7), B else.
  // LDS dest = s*16 (A then B contiguous). Global chunk gc = pc ^ (row&7).
  const unsigned char* gptr[6];
#pragma unroll
  for (int r = 0; r < 6; ++r) {
    int s   = r * 768 + wv * 64 + lane;
    int mat = (s >= 2304);
    int sm  = s - mat * 2304;
    int row = sm >> 3, pc = sm & 7;
    int gc  = pc ^ (row & 7);
    const unsigned char* base = mat ? (tf8 + (size_t)(bj * 288 + row) * 3840)
                                    : (qf8 + (size_t)(bi * 288 + row) * 3840);
    gptr[r] = base + gc * 16;
  }

  int buf = 0;
#pragma unroll
  for (int r = 0; r < 6; ++r)
    __builtin_amdgcn_global_load_lds((const AS1 void*)(gptr[r]),
                                     (AS3 void*)(smem + (r * 768 + wv * 64) * 16), 16, 0, 0);

  const int arow0 = wrow * 48 + l16;
  const int bcol0 = wcol * 144 + l16;

  for (int kt = 0; kt < 30; ++kt) {
    __syncthreads();  // drains vmcnt(0): current buf staged; prev buf reads done
    if (kt < 29) {
      int nb = buf ^ 1;
#pragma unroll
      for (int r = 0; r < 6; ++r)
        __builtin_amdgcn_global_load_lds((const AS1 void*)(gptr[r] + (kt + 1) * 128),
                                         (AS3 void*)(smem + nb * 73728 + (r * 768 + wv * 64) * 16),
                                         16, 0, 0);
    }
    const char* A = smem + buf * 73728;
    const char* B = A + 36864;

    v8i av[3];
#pragma unroll
    for (int sr = 0; sr < 3; ++sr) {
      int row = arow0 + sr * 16;
      int sw  = row & 7;
      int p0  = (quad * 2) ^ sw, p1 = (quad * 2 + 1) ^ sw;
      int4 lo = *(const int4*)(A + row * 128 + p0 * 16);
      int4 hi = *(const int4*)(A + row * 128 + p1 * 16);
      v8i v;
      v[0] = lo.x; v[1] = lo.y; v[2] = lo.z; v[3] = lo.w;
      v[4] = hi.x; v[5] = hi.y; v[6] = hi.z; v[7] = hi.w;
      av[sr] = v;
    }
#pragma unroll
    for (int c = 0; c < 9; ++c) {
      int col = bcol0 + c * 16;
      int sw  = col & 7;
      int p0  = (quad * 2) ^ sw, p1 = (quad * 2 + 1) ^ sw;
      int4 lo = *(const int4*)(B + col * 128 + p0 * 16);
      int4 hi = *(const int4*)(B + col * 128 + p1 * 16);
      v8i bv;
      bv[0] = lo.x; bv[1] = lo.y; bv[2] = lo.z; bv[3] = lo.w;
      bv[4] = hi.x; bv[5] = hi.y; bv[6] = hi.z; bv[7] = hi.w;
      acc[0][c] = __builtin_amdgcn_mfma_scale_f32_16x16x128_f8f6f4(
          av[0], bv, acc[0][c], 0, 0, 0, 0x7f7f7f7f, 0, 0x7f7f7f7f);
      acc[1][c] = __builtin_amdgcn_mfma_scale_f32_16x16x128_f8f6f4(
          av[1], bv, acc[1][c], 0, 0, 0, 0x7f7f7f7f, 0, 0x7f7f7f7f);
      acc[2][c] = __builtin_amdgcn_mfma_scale_f32_16x16x128_f8f6f4(
          av[2], bv, acc[2][c], 0, 0, 0, 0x7f7f7f7f, 0, 0x7f7f7f7f);
    }
    buf ^= 1;
  }

  // -------- epilogue: 18 bands of 16 rows; rowmax over each 9-col group --------
  __syncthreads();
  float* scr = (float*)smem;  // [16][288]
#pragma unroll
  for (int b = 0; b < 18; ++b) {
    const int bw = b / 3, bs = b - bw * 3;
    if (wrow == bw) {
#pragma unroll
      for (int c = 0; c < 9; ++c)
#pragma unroll
        for (int r = 0; r < 4; ++r)
          scr[(quad * 4 + r) * 288 + wcol * 144 + c * 16 + l16] = acc[bs][c][r] * (1.f / 256.f);
    }
    __syncthreads();
    if (tid < 512) {
      int row = tid >> 5, jg = tid & 31;
      const float* p = scr + row * 288 + jg * 9;
      float m = p[0];
#pragma unroll
      for (int k = 1; k < 9; ++k) m = fmaxf(m, p[k]);
      cmax[(size_t)(bi * 288 + b * 16 + row) * 512 + bj * 32 + jg] = m;
    }
    __syncthreads();
  }
}

// ---------------- mean over o (9 rows) -> f2f[512][512] ----------------
__global__ __launch_bounds__(512) void mean9_kernel(const float* __restrict__ cmax,
                                                    float* __restrict__ f2f) {
  int i = blockIdx.x, j = threadIdx.x;
  float s = 0.f;
#pragma unroll
  for (int o = 0; o < 9; ++o) s += cmax[(size_t)(i * 9 + o) * 512 + j];
  f2f[i * 512 + j] = s * (1.f / 9.f);
}

// ---------------- conv1: 1->32ch 3x3 same + relu + 2x2 maxpool, 512^2 -> 256^2 ----------------
__global__ __launch_bounds__(256) void conv1_kernel(const float* __restrict__ in,
                                                    const float* __restrict__ w1,
                                                    const float* __restrict__ b1,
                                                    float* __restrict__ out) {
  __shared__ float tile[34 * 36];
  __shared__ float wl[320];
  int t = blockIdx.x;
  int ty0 = (t >> 4) * 32, tx0 = (t & 15) * 32;
  int py = threadIdx.x >> 4, px = threadIdx.x & 15;

  for (int idx = threadIdx.x; idx < 320; idx += 256)
    wl[idx] = (idx < 288) ? w1[idx] : b1[idx - 288];
  for (int idx = threadIdx.x; idx < 34 * 34; idx += 256) {
    int r = idx / 34, c = idx % 34;
    int gy = ty0 + r - 1, gx = tx0 + c - 1;
    tile[r * 36 + c] = ((unsigned)gy < 512u && (unsigned)gx < 512u) ? in[gy * 512 + gx] : 0.f;
  }
  __syncthreads();

  float win[4][4];
#pragma unroll
  for (int r = 0; r < 4; ++r)
#pragma unroll
    for (int c = 0; c < 4; ++c)
      win[r][c] = tile[(2 * py + r) * 36 + 2 * px + c];

  int gy2 = (t >> 4) * 16 + py, gx2 = (t & 15) * 16 + px;
#pragma unroll 1
  for (int ch = 0; ch < 32; ++ch) {
    float w[9];
#pragma unroll
    for (int k = 0; k < 9; ++k) w[k] = wl[ch * 9 + k];
    float m = -INFINITY;
#pragma unroll
    for (int a = 0; a < 2; ++a)
#pragma unroll
      for (int b = 0; b < 2; ++b) {
        float s = 0.f;
#pragma unroll
        for (int ky = 0; ky < 3; ++ky)
#pragma unroll
          for (int kx = 0; kx < 3; ++kx) s += win[a + ky][b + kx] * w[ky * 3 + kx];
        m = fmaxf(m, s);
      }
    out[ch * 65536 + gy2 * 256 + gx2] = fmaxf(m + wl[288 + ch], 0.f);
  }
}

// ---------------- conv2: 32->64ch 3x3 same + relu + 2x2 maxpool, 256^2 -> 128^2 ----------------
// 4 co/block -> 1024 blocks (4/CU, 16 waves/CU). Weights in LDS, double-buffered input.
__global__ __launch_bounds__(256) void conv2_kernel(const float* __restrict__ in,
                                                    const float* __restrict__ w2,
                                                    const float* __restrict__ b2,
                                                    float* __restrict__ out) {
  __shared__ __align__(16) float wlds[32 * 4 * 12];   // 6144 B
  __shared__ float tile[2][2][34 * 36];               // 19584 B
  const int tid = threadIdx.x;
  int cog = blockIdx.x >> 6;          // 0..15 -> 4 output channels
  int t   = blockIdx.x & 63;          // 8x8 tiles of 32x32 pre-pool
  int ty0 = (t >> 3) * 32, tx0 = (t & 7) * 32;
  int py = tid >> 4, px = tid & 15;

  for (int idx = tid; idx < 1152; idx += 256) {
    int co = idx / 288, rem = idx % 288, ci = rem / 9, k = rem % 9;
    wlds[(ci * 4 + co) * 12 + k] = w2[((cog * 4 + co) * 32 + ci) * 9 + k];
  }
  for (int idx = tid; idx < 2312; idx += 256) {
    int pl = idx / 1156, rc = idx % 1156, r = rc / 34, c = rc % 34;
    int gy = ty0 + r - 1, gx = tx0 + c - 1;
    tile[0][pl][r * 36 + c] = ((unsigned)gy < 256u && (unsigned)gx < 256u)
                                  ? in[pl * 65536 + gy * 256 + gx] : 0.f;
  }
  __syncthreads();

  float acc[4][4];
#pragma unroll
  for (int p = 0; p < 4; ++p)
#pragma unroll
    for (int co = 0; co < 4; ++co) acc[p][co] = 0.f;

#pragma unroll 1
  for (int cb = 0; cb < 16; ++cb) {
    int buf = cb & 1;
    float pf[10];
    if (cb < 15) {
#pragma unroll
      for (int i = 0; i < 10; ++i) {
        int idx = tid + i * 256;
        float v = 0.f;
        if (idx < 2312) {
          int pl = idx / 1156, rc = idx % 1156, r = rc / 34, c = rc % 34;
          int gy = ty0 + r - 1, gx = tx0 + c - 1;
          if ((unsigned)gy < 256u && (unsigned)gx < 256u)
            v = in[((cb + 1) * 2 + pl) * 65536 + gy * 256 + gx];
        }
        pf[i] = v;
      }
    }
#pragma unroll
    for (int pl = 0; pl < 2; ++pl) {
      float win[4][4];
#pragma unroll
      for (int r = 0; r < 4; ++r) {
        float2 lo = *(const float2*)&tile[buf][pl][(2 * py + r) * 36 + 2 * px];
        float2 hi = *(const float2*)&tile[buf][pl][(2 * py + r) * 36 + 2 * px + 2];
        win[r][0] = lo.x; win[r][1] = lo.y; win[r][2] = hi.x; win[r][3] = hi.y;
      }
      int ci = cb * 2 + pl;
#pragma unroll
      for (int co = 0; co < 4; ++co) {
        const float* wp = &wlds[(ci * 4 + co) * 12];
        float4 w0 = *(const float4*)wp;
        float4 w1v = *(const float4*)(wp + 4);
        float w8 = wp[8];
        float w[9] = {w0.x, w0.y, w0.z, w0.w, w1v.x, w1v.y, w1v.z, w1v.w, w8};
#pragma unroll
        for (int a = 0; a < 2; ++a)
#pragma unroll
          for (int b = 0; b < 2; ++b) {
            float s = acc[a * 2 + b][co];
#pragma unroll
            for (int ky = 0; ky < 3; ++ky)
#pragma unroll
              for (int kx = 0; kx < 3; ++kx) s += win[a + ky][b + kx] * w[ky * 3 + kx];
            acc[a * 2 + b][co] = s;
          }
      }
    }
    if (cb < 15) {
#pragma unroll
      for (int i = 0; i < 10; ++i) {
        int idx = tid + i * 256;
        if (idx < 2312) {
          int pl = idx / 1156, rc = idx % 1156, r = rc / 34, c = rc % 34;
          tile[buf ^ 1][pl][r * 36 + c] = pf[i];
        }
      }
    }
    __syncthreads();
  }

  int gy2 = (t >> 3) * 16 + py, gx2 = (t & 7) * 16 + px;
#pragma unroll
  for (int co = 0; co < 4; ++co) {
    float m = fmaxf(fmaxf(acc[0][co], acc[1][co]), fmaxf(acc[2][co], acc[3][co]));
    out[(cog * 4 + co) * 16384 + gy2 * 128 + gx2] = fmaxf(m + b2[cog * 4 + co], 0.f);
  }
}

// ---------------- conv3: 64->128ch 3x3 same + relu, 128^2 ----------------
// 32x32 spatial tile, 4 px/thread (2x2), 4 co/block -> 512 blocks. Weights in LDS,
// 4 ci planes/round double-buffered with register prefetch.
__global__ __launch_bounds__(256) void conv3_kernel(const float* __restrict__ in,
                                                    const float* __restrict__ w3,
                                                    const float* __restrict__ b3,
                                                    float* __restrict__ out) {
  __shared__ __align__(16) float wlds[64 * 4 * 12];   // 12288 B
  __shared__ float tile[2][4][34 * 36];               // 39168 B
  const int tid = threadIdx.x;
  int cog = blockIdx.x >> 4;          // 0..31 -> 4 output channels
  int t   = blockIdx.x & 15;          // 4x4 tiles of 32x32
  int ty0 = (t >> 2) * 32, tx0 = (t & 3) * 32;
  int py = tid >> 4, px = tid & 15;

  for (int idx = tid; idx < 2304; idx += 256) {
    int co = idx / 576, rem = idx % 576, ci = rem / 9, k = rem % 9;
    wlds[(ci * 4 + co) * 12 + k] = w3[((cog * 4 + co) * 64 + ci) * 9 + k];
  }
  for (int idx = tid; idx < 4624; idx += 256) {
    int pl = idx / 1156, rc = idx % 1156, r = rc / 34, c = rc % 34;
    int gy = ty0 + r - 1, gx = tx0 + c - 1;
    tile[0][pl][r * 36 + c] = ((unsigned)gy < 128u && (unsigned)gx < 128u)
                                  ? in[pl * 16384 + gy * 128 + gx] : 0.f;
  }
  __syncthreads();

  float acc[4][4];
#pragma unroll
  for (int p = 0; p < 4; ++p)
#pragma unroll
    for (int co = 0; co < 4; ++co) acc[p][co] = 0.f;

#pragma unroll 1
  for (int cb = 0; cb < 16; ++cb) {
    int buf = cb & 1;
    float pf[19];
    if (cb < 15) {
#pragma unroll
      for (int i = 0; i < 19; ++i) {
        int idx = tid + i * 256;
        float v = 0.f;
        if (idx < 4624) {
          int pl = idx / 1156, rc = idx % 1156, r = rc / 34, c = rc % 34;
          int gy = ty0 + r - 1, gx = tx0 + c - 1;
          if ((unsigned)gy < 128u && (unsigned)gx < 128u)
            v = in[((cb + 1) * 4 + pl) * 16384 + gy * 128 + gx];
        }
        pf[i] = v;
      }
    }
#pragma unroll
    for (int pl = 0; pl < 4; ++pl) {
      float win[4][4];
#pragma unroll
      for (int r = 0; r < 4; ++r) {
        float2 lo = *(const float2*)&tile[buf][pl][(2 * py + r) * 36 + 2 * px];
        float2 hi = *(const float2*)&tile[buf][pl][(2 * py + r) * 36 + 2 * px + 2];
        win[r][0] = lo.x; win[r][1] = lo.y; win[r][2] = hi.x; win[r][3] = hi.y;
      }
      int ci = cb * 4 + pl;
#pragma unroll
      for (int co = 0; co < 4; ++co) {
        const float* wp = &wlds[(ci * 4 + co) * 12];
        float4 w0 = *(const float4*)wp;
        float4 w1v = *(const float4*)(wp + 4);
        float w8 = wp[8];
        float w[9] = {w0.x, w0.y, w0.z, w0.w, w1v.x, w1v.y, w1v.z, w1v.w, w8};
#pragma unroll
        for (int a = 0; a < 2; ++a)
#pragma unroll
          for (int b = 0; b < 2; ++b) {
            float s = acc[a * 2 + b][co];
#pragma unroll
            for (int ky = 0; ky < 3; ++ky)
#pragma unroll
              for (int kx = 0; kx < 3; ++kx) s += win[a + ky][b + kx] * w[ky * 3 + kx];
            acc[a * 2 + b][co] = s;
          }
      }
    }
    if (cb < 15) {
#pragma unroll
      for (int i = 0; i < 19; ++i) {
        int idx = tid + i * 256;
        if (idx < 4624) {
          int pl = idx / 1156, rc = idx % 1156, r = rc / 34, c = rc % 34;
          tile[buf ^ 1][pl][r * 36 + c] = pf[i];
        }
      }
    }
    __syncthreads();
  }

#pragma unroll
  for (int co = 0; co < 4; ++co) {
    float bias = b3[cog * 4 + co];
    float* op = out + (cog * 4 + co) * 16384;
#pragma unroll
    for (int a = 0; a < 2; ++a)
#pragma unroll
      for (int b = 0; b < 2; ++b)
        op[(ty0 + 2 * py + a) * 128 + tx0 + 2 * px + b] = fmaxf(acc[a * 2 + b][co] + bias, 0.f);
  }
}

// ---------------- 1x1 conv (128->1) + bias + clip + rowmax over x ----------------
__global__ __launch_bounds__(512) void convf_kernel(const float* __restrict__ in,
                                                    const float* __restrict__ wf,
                                                    const float* __restrict__ bfp,
                                                    float* __restrict__ rowm) {
  __shared__ float part[512];
  int y = blockIdx.x, tid = threadIdx.x;
  int pt = tid >> 7, x = tid & 127;
  float acc = 0.f;
  const float* ip = in + y * 128 + x;
  for (int ci = pt * 32; ci < pt * 32 + 32; ++ci) acc += ip[ci * 16384] * wf[ci];
  part[tid] = acc;
  __syncthreads();
  if (tid < 128) {
    float s = part[tid] + part[tid + 128] + part[tid + 256] + part[tid + 384] + bfp[0];
    part[tid] = fminf(fmaxf(s, -1.f), 1.f);
  }
  __syncthreads();
  if (tid < 64) {
    float m = fmaxf(part[tid], part[tid + 64]);
    for (int off = 32; off; off >>= 1) m = fmaxf(m, __shfl_down(m, off, 64));
    if (tid == 0) rowm[y] = m;
  }
}

// ---------------- mean over rows -> scalar ----------------
__global__ __launch_bounds__(128) void final_kernel(const float* __restrict__ rowm,
                                                    float* __restrict__ out) {
  int x = threadIdx.x;
  float v = rowm[x];
  for (int off = 32; off; off >>= 1) v += __shfl_down(v, off, 64);
  __shared__ float red[2];
  if ((x & 63) == 0) red[x >> 6] = v;
  __syncthreads();
  if (x == 0) out[0] = (red[0] + red[1]) * (1.f / 128.f);
}

extern "C" void kernel_launch(void* const* d_in, const int* in_sizes, int n_in,
                              void* d_out, int out_size, void* d_ws, size_t ws_size,
                              hipStream_t stream) {
  const float* q  = (const float*)d_in[0];
  const float* t  = (const float*)d_in[1];
  const float* w1 = (const float*)d_in[2];
  const float* b1 = (const float*)d_in[3];
  const float* w2 = (const float*)d_in[4];
  const float* b2 = (const float*)d_in[5];
  const float* w3 = (const float*)d_in[6];
  const float* b3 = (const float*)d_in[7];
  const float* wf = (const float*)d_in[8];
  const float* bf = (const float*)d_in[9];
  float* out = (float*)d_out;
  char* ws = (char*)d_ws;

  unsigned char* qf8 = (unsigned char*)(ws + 0);          // 17,694,720
  unsigned char* tf8 = (unsigned char*)(ws + 17694720);   // 17,694,720
  float* cmax = (float*)(ws + 35389440);                  // 9,437,184
  float* f2f  = (float*)(ws + 44826624);                  // 512x512
  float* x1   = (float*)(ws + 45875200);                  // 32x256x256
  float* x2b  = (float*)(ws + 54263808);                  // 64x128x128
  float* x3   = (float*)(ws + 58458112);                  // 128x128x128
  float* rowm = (float*)(ws + 66846720);                  // 128

  cvt_fp8_kernel<<<4320, 256, 0, stream>>>(q, (unsigned int*)qf8, 1105920);
  cvt_fp8_kernel<<<4320, 256, 0, stream>>>(t, (unsigned int*)tf8, 1105920);
  gemm_cmax_kernel<<<dim3(16, 16), 768, 0, stream>>>(qf8, tf8, cmax);
  mean9_kernel<<<512, 512, 0, stream>>>(cmax, f2f);
  conv1_kernel<<<256, 256, 0, stream>>>(f2f, w1, b1, x1);
  conv2_kernel<<<1024, 256, 0, stream>>>(x1, w2, b2, x2b);
  conv3_kernel<<<512, 256, 0, stream>>>(x2b, w3, b3, x3);
  convf_kernel<<<128, 512, 0, stream>>>(x3, wf, bf, rowm);
  final_kernel<<<1, 128, 0, stream>>>(rowm, out);
}